// Round 4
// baseline (282.662 us; speedup 1.0000x reference)
//
#include <hip/hip_runtime.h>
#include <hip/hip_bf16.h>
#include <cstddef>

#define B_   256
#define P_   196
#define DE_  2048
#define DD_  512
#define DA_  512
#define M_   (B_*P_)   // 50176

#define BM   64        // grid 784 exact (50176/64), ~3 blocks/CU queued, 2 resident
#define KT   32        // K per stage

typedef __attribute__((ext_vector_type(4))) float f32x4;
typedef __attribute__((ext_vector_type(8))) short s16x8;

static __device__ __forceinline__ short f2bf(float x) {
    __hip_bfloat16 h = __float2bfloat16(x);
    return *reinterpret_cast<short*>(&h);
}

#define GLOAD_LDS16(g, l) __builtin_amdgcn_global_load_lds( \
    (const __attribute__((address_space(1))) void*)(g),     \
    (__attribute__((address_space(3))) void*)(l), 16, 0, 0)

// ---------------------------------------------------------------------------
// Kernel 0: pack W_enc [K][N] fp32 -> bf16 fragment-ready + XOR-swizzled
// layout: [kt][n][slot'8], slot' = slot ^ ((n>>1)&3)
// ---------------------------------------------------------------------------
__global__ void pack_wenc(const float* __restrict__ W, __hip_bfloat16* __restrict__ out) {
    __shared__ float lds[KT][128 + 1];
    const int kt = blockIdx.x;
    const int n0 = blockIdx.y * 128;
    const int t  = threadIdx.x;
#pragma unroll
    for (int i = 0; i < 16; ++i) {
        int e  = t + i * 256;
        int kl = e >> 7;
        int nl = e & 127;
        lds[kl][nl] = W[(size_t)(kt * KT + kl) * DA_ + n0 + nl];
    }
    __syncthreads();
    short* o16 = reinterpret_cast<short*>(out);
#pragma unroll
    for (int i = 0; i < 2; ++i) {
        int task = t + i * 256;
        int nl   = task >> 2;
        int s    = task & 3;
        int n    = n0 + nl;
        int sp   = s ^ ((n >> 1) & 3);
        s16x8 w;
#pragma unroll
        for (int j = 0; j < 8; ++j)
            w[j] = f2bf(lds[s * 8 + j][nl]);
        *reinterpret_cast<s16x8*>(o16 + (size_t)kt * (DA_ * KT) + n * KT + sp * 8) = w;
    }
}

// ---------------------------------------------------------------------------
// Kernel 1: att2p[b][a] = dh[b,:] @ W_dec[:,a] + b_dec[a] + b_enc[a]
// ---------------------------------------------------------------------------
__global__ __launch_bounds__(512) void att2_kernel(
        const float* __restrict__ dh, const float* __restrict__ W_dec,
        const float* __restrict__ b_dec, const float* __restrict__ b_enc,
        float* __restrict__ att2p) {
    __shared__ float s_dh[DD_];
    const int b = blockIdx.x;
    const int a = threadIdx.x;
    s_dh[a] = dh[(size_t)b * DD_ + a];
    __syncthreads();
    float acc = 0.f;
#pragma unroll 8
    for (int k = 0; k < DD_; ++k)
        acc += s_dh[k] * W_dec[(size_t)k * DA_ + a];
    att2p[(size_t)b * DA_ + a] = acc + b_dec[a] + b_enc[a];
}

// ---------------------------------------------------------------------------
// Kernel 2: GEMM 50176x512x2048 bf16 MFMA + fused relu/dot epilogue.
// 256 threads = 4 waves; tile 64 x 512; wave w owns cols [w*128, w*128+128).
// Double-buffered LDS, raw s_barrier + counted vmcnt, A prefetched 2 tiles
// ahead in regs, B via global_load_lds. 2 blocks/CU resident (TLP overlap).
// ---------------------------------------------------------------------------
__global__ __launch_bounds__(256, 2) void gemm_att(
        const float* __restrict__ enc, const __hip_bfloat16* __restrict__ Bp,
        const float* __restrict__ att2p, const float* __restrict__ Wfull,
        const float* __restrict__ bfull, float* __restrict__ att) {
    __shared__ __hip_bfloat16 a_lds0[BM * KT];      // 4 KB each
    __shared__ __hip_bfloat16 a_lds1[BM * KT];
    __shared__ __hip_bfloat16 b_lds0[DA_ * KT];     // 32 KB each
    __shared__ __hip_bfloat16 b_lds1[DA_ * KT];
    __shared__ float red[BM][4];                    // 1 KB

    const int tid  = threadIdx.x;
    const int wave = tid >> 6;
    const int lane = tid & 63;
    const int g    = lane >> 4;        // k-group 0..3
    const int c    = lane & 15;
    const int block_row = blockIdx.x * BM;
    const int nbase = wave * 128;
    const int slot8 = (g ^ ((c >> 1) & 3)) * 8;

    // A staging: one task per thread: row ar (0..63), k-slot aq (0..3)
    const int ar = tid >> 2;
    const int aq = tid & 3;
    const int a_woff = ar * KT + (aq ^ ((ar >> 1) & 3)) * 8;
    const float* ap = enc + (size_t)(block_row + ar) * DE_ + aq * 8;

    f32x4 acc[4][8] = {};
    f32x4 pa0, pa1, pb0, pb1;   // A prefetch register sets

#define STORE_A(dstbase, v0, v1) do {                                   \
        s16x8 w_;                                                       \
        w_[0]=f2bf((v0).x); w_[1]=f2bf((v0).y); w_[2]=f2bf((v0).z); w_[3]=f2bf((v0).w); \
        w_[4]=f2bf((v1).x); w_[5]=f2bf((v1).y); w_[6]=f2bf((v1).z); w_[7]=f2bf((v1).w); \
        *reinterpret_cast<s16x8*>((dstbase) + a_woff) = w_;             \
    } while (0)

#define ISSUE_B(T, dstb) do {                                           \
        const char* bs_ = (const char*)Bp + (size_t)(T) * (DA_*KT*2) + (size_t)tid * 16; \
        char* bd_ = (char*)(dstb) + (size_t)tid * 16;                   \
        _Pragma("unroll")                                               \
        for (int i_ = 0; i_ < 8; ++i_)                                  \
            GLOAD_LDS16(bs_ + i_ * 4096, bd_ + i_ * 4096);              \
    } while (0)

#define FRAGS_MFMA(abuf, bbuf) do {                                     \
        s16x8 af[4], bf[8];                                             \
        _Pragma("unroll")                                               \
        for (int mt = 0; mt < 4; ++mt)                                  \
            af[mt] = *reinterpret_cast<const s16x8*>((abuf) + (mt*16 + c) * KT + slot8); \
        _Pragma("unroll")                                               \
        for (int nt = 0; nt < 8; ++nt)                                  \
            bf[nt] = *reinterpret_cast<const s16x8*>((bbuf) + (nbase + nt*16 + c) * KT + slot8); \
        _Pragma("unroll")                                               \
        for (int mt = 0; mt < 4; ++mt)                                  \
            _Pragma("unroll")                                           \
            for (int nt = 0; nt < 8; ++nt)                              \
                acc[mt][nt] = __builtin_amdgcn_mfma_f32_16x16x32_bf16(  \
                                  af[mt], bf[nt], acc[mt][nt], 0, 0, 0);\
    } while (0)

#define FENCE_AFTER_BARRIER() do {                                      \
        asm volatile("" ::: "memory");                                  \
        __builtin_amdgcn_sched_barrier(0);                              \
    } while (0)

    // ---- prologue: tile 0 staged, A(1) in flight ----
    pa0 = *reinterpret_cast<const f32x4*>(ap);          // A(0)
    pa1 = *reinterpret_cast<const f32x4*>(ap + 4);
    ISSUE_B(0, b_lds0);
    pb0 = *reinterpret_cast<const f32x4*>(ap + KT);     // A(1)
    pb1 = *reinterpret_cast<const f32x4*>(ap + KT + 4);
    STORE_A(a_lds0, pa0, pa1);                          // waits A(0) only (FIFO vmcnt)
    asm volatile("s_waitcnt vmcnt(2) lgkmcnt(0)" ::: "memory");  // B(0) done, A(1) in flight
    __builtin_amdgcn_s_barrier();
    FENCE_AFTER_BARRIER();

    const float* ap_it = ap;
#pragma clang loop unroll(disable)
    for (int kt = 0; kt < 62; kt += 2) {
        // even: compute buf0(kt); stage A(kt+1) from regs; issue B(kt+1), A(kt+2)
        ISSUE_B(kt + 1, b_lds1);
        pa0 = *reinterpret_cast<const f32x4*>(ap_it + 2 * KT);
        pa1 = *reinterpret_cast<const f32x4*>(ap_it + 2 * KT + 4);
        FRAGS_MFMA(a_lds0, b_lds0);
        STORE_A(a_lds1, pb0, pb1);
        asm volatile("s_waitcnt vmcnt(2) lgkmcnt(0)" ::: "memory");
        __builtin_amdgcn_s_barrier();
        FENCE_AFTER_BARRIER();
        // odd: compute buf1(kt+1); stage A(kt+2); issue B(kt+2), A(kt+3)
        ISSUE_B(kt + 2, b_lds0);
        pb0 = *reinterpret_cast<const f32x4*>(ap_it + 3 * KT);
        pb1 = *reinterpret_cast<const f32x4*>(ap_it + 3 * KT + 4);
        FRAGS_MFMA(a_lds1, b_lds1);
        STORE_A(a_lds0, pa0, pa1);
        asm volatile("s_waitcnt vmcnt(2) lgkmcnt(0)" ::: "memory");
        __builtin_amdgcn_s_barrier();
        FENCE_AFTER_BARRIER();
        ap_it += 2 * KT;
    }
    // t = 62: compute buf0(62); stage A(63); issue B(63)
    ISSUE_B(63, b_lds1);
    FRAGS_MFMA(a_lds0, b_lds0);
    STORE_A(a_lds1, pb0, pb1);
    asm volatile("s_waitcnt vmcnt(0) lgkmcnt(0)" ::: "memory");
    __builtin_amdgcn_s_barrier();
    FENCE_AFTER_BARRIER();
    // t = 63: pure compute
    FRAGS_MFMA(a_lds1, b_lds1);

    // ---- fused epilogue: att[R] = sum_n relu(att1+att2)*Wfull ----
    const int b0    = block_row / P_;
    const int b1    = min(b0 + 1, B_ - 1);
    const int split = (b0 + 1) * P_;
    float wf[8], a20[8], a21[8];
#pragma unroll
    for (int nt = 0; nt < 8; ++nt) {
        const int n = nbase + nt * 16 + c;
        wf[nt]  = Wfull[n];
        a20[nt] = att2p[(size_t)b0 * DA_ + n];
        a21[nt] = att2p[(size_t)b1 * DA_ + n];
    }
#pragma unroll
    for (int mt = 0; mt < 4; ++mt) {
#pragma unroll
        for (int q = 0; q < 4; ++q) {
            const int row_local = mt * 16 + g * 4 + q;
            const int R = block_row + row_local;
            const bool hi = (R >= split);
            float s = 0.f;
#pragma unroll
            for (int nt = 0; nt < 8; ++nt) {
                float a2 = hi ? a21[nt] : a20[nt];
                float v  = acc[mt][nt][q] + a2;
                v = fmaxf(v, 0.f);
                s += v * wf[nt];
            }
#pragma unroll
            for (int off = 1; off < 16; off <<= 1)
                s += __shfl_xor(s, off, 64);
            if (c == 0) red[row_local][wave] = s;
        }
    }
    __syncthreads();
    if (tid < BM) {
        float t = 0.f;
#pragma unroll
        for (int w = 0; w < 4; ++w) t += red[tid][w];
        att[block_row + tid] = t + bfull[0];
    }
#undef STORE_A
#undef ISSUE_B
#undef FRAGS_MFMA
#undef FENCE_AFTER_BARRIER
}

// ---------------------------------------------------------------------------
// Kernel 3: softmax over P per batch -> alpha
// ---------------------------------------------------------------------------
__global__ __launch_bounds__(256) void softmax_kernel(
        const float* __restrict__ att, float* __restrict__ alpha) {
    const int b = blockIdx.x;
    const int t = threadIdx.x;
    __shared__ float sred[4];
    float v = (t < P_) ? att[(size_t)b * P_ + t] : -1e30f;
    float m = v;
#pragma unroll
    for (int off = 1; off < 64; off <<= 1) m = fmaxf(m, __shfl_xor(m, off, 64));
    if ((t & 63) == 0) sred[t >> 6] = m;
    __syncthreads();
    const float mall = fmaxf(fmaxf(sred[0], sred[1]), fmaxf(sred[2], sred[3]));
    __syncthreads();
    float e = (t < P_) ? expf(v - mall) : 0.f;
    float s = e;
#pragma unroll
    for (int off = 1; off < 64; off <<= 1) s += __shfl_xor(s, off, 64);
    if ((t & 63) == 0) sred[t >> 6] = s;
    __syncthreads();
    const float stot = sred[0] + sred[1] + sred[2] + sred[3];
    if (t < P_) alpha[(size_t)b * P_ + t] = e / stot;
}

// ---------------------------------------------------------------------------
// Kernel 4: context[b][e] = sum_p alpha[b][p] * enc[b][p][e]
// ---------------------------------------------------------------------------
__global__ __launch_bounds__(256) void context_kernel(
        const float* __restrict__ enc, const float* __restrict__ alpha,
        float* __restrict__ ctx) {
    const int b = blockIdx.x;
    const int e = blockIdx.y * 1024 + threadIdx.x * 4;
    __shared__ float s_alpha[P_];
    if (threadIdx.x < P_) s_alpha[threadIdx.x] = alpha[(size_t)b * P_ + threadIdx.x];
    __syncthreads();
    f32x4 acc = {0.f, 0.f, 0.f, 0.f};
    const float* base = enc + (size_t)b * P_ * DE_ + e;
#pragma unroll 4
    for (int p = 0; p < P_; ++p) {
        f32x4 v = *reinterpret_cast<const f32x4*>(base + (size_t)p * DE_);
        acc += s_alpha[p] * v;
    }
    *reinterpret_cast<f32x4*>(ctx + (size_t)b * DE_ + e) = acc;
}

// ---------------------------------------------------------------------------
extern "C" void kernel_launch(void* const* d_in, const int* in_sizes, int n_in,
                              void* d_out, int out_size, void* d_ws, size_t ws_size,
                              hipStream_t stream) {
    const float* enc    = (const float*)d_in[0];
    const float* dh     = (const float*)d_in[1];
    const float* W_enc  = (const float*)d_in[2];
    const float* b_enc  = (const float*)d_in[3];
    const float* W_dec  = (const float*)d_in[4];
    const float* b_dec  = (const float*)d_in[5];
    const float* W_full = (const float*)d_in[6];
    const float* b_full = (const float*)d_in[7];

    float* out       = (float*)d_out;
    float* ctx_out   = out;                       // [B,DE]
    float* alpha_out = out + (size_t)B_ * DE_;    // [B,P]

    char* ws = (char*)d_ws;
    __hip_bfloat16* Bp = (__hip_bfloat16*)ws;                        // 2 MB
    float* att2p = (float*)(ws + 2u * 1024 * 1024);                  // 512 KB
    float* att   = (float*)(ws + 2u * 1024 * 1024 + 512u * 1024);    // 200 KB

    pack_wenc   <<<dim3(64, 4),     256, 0, stream>>>(W_enc, Bp);
    att2_kernel <<<B_,              512, 0, stream>>>(dh, W_dec, b_dec, b_enc, att2p);
    gemm_att    <<<M_ / BM,         256, 0, stream>>>(enc, Bp, att2p, W_full, b_full, att);
    softmax_kernel<<<B_,            256, 0, stream>>>(att, alpha_out);
    context_kernel<<<dim3(B_, 2),   256, 0, stream>>>(enc, alpha_out, ctx_out);
}

// Round 5
// 275.276 us; speedup vs baseline: 1.0268x; 1.0268x over previous
//
#include <hip/hip_runtime.h>
#include <hip/hip_bf16.h>
#include <cstddef>

#define B_   256
#define P_   196
#define DE_  2048
#define DD_  512
#define DA_  512
#define M_   (B_*P_)   // 50176

#define BM   64        // grid 784 (exact), 2 blocks/CU resident
#define KT   32        // K per step
#define NKT  (DE_/KT)  // 64

typedef __attribute__((ext_vector_type(4))) float f32x4;
typedef __attribute__((ext_vector_type(8))) short s16x8;

static __device__ __forceinline__ short f2bf(float x) {
    __hip_bfloat16 h = __float2bfloat16(x);
    return *reinterpret_cast<short*>(&h);
}

// ---------------------------------------------------------------------------
// Kernel 0: pack W_enc [K][N] fp32 -> bf16 per-fragment layout:
//   unit index u = (kt*32 + gf)*64 + lane   (each unit = 8 bf16 = 16 B)
//   content: lane l, j=0..7 -> W[kt*32 + (l>>4)*8 + j][gf*16 + (l&15)]
// A wave's B-frag load is then one coalesced global_load_dwordx4 (1 KB).
// ---------------------------------------------------------------------------
__global__ __launch_bounds__(256) void pack_wenc(
        const float* __restrict__ W, __hip_bfloat16* __restrict__ out) {
    __shared__ float lds[KT][DA_];          // 64 KB
    const int kt = blockIdx.x;              // 0..63
    const int t  = threadIdx.x;             // 0..255
#pragma unroll
    for (int i = 0; i < 64; ++i) {
        int e = i * 256 + t;                // 0..16383
        int k = e >> 9, n = e & 511;
        lds[k][n] = W[(size_t)(kt * KT + k) * DA_ + n];
    }
    __syncthreads();
    short* o = reinterpret_cast<short*>(out) + (size_t)kt * (32 * 64 * 8);
#pragma unroll
    for (int i = 0; i < 8; ++i) {
        int idx  = i * 256 + t;             // 0..2047
        int gf   = idx >> 6;                // 0..31
        int lane = idx & 63;
        int g = lane >> 4, c = lane & 15;
        s16x8 w;
#pragma unroll
        for (int j = 0; j < 8; ++j)
            w[j] = f2bf(lds[g * 8 + j][gf * 16 + c]);
        *reinterpret_cast<s16x8*>(o + (size_t)idx * 8) = w;
    }
}

// ---------------------------------------------------------------------------
// Kernel 1: att2p[b][a] = dh[b,:] @ W_dec[:,a] + b_dec[a] + b_enc[a]
// ---------------------------------------------------------------------------
__global__ __launch_bounds__(512) void att2_kernel(
        const float* __restrict__ dh, const float* __restrict__ W_dec,
        const float* __restrict__ b_dec, const float* __restrict__ b_enc,
        float* __restrict__ att2p) {
    __shared__ float s_dh[DD_];
    const int b = blockIdx.x;
    const int a = threadIdx.x;
    s_dh[a] = dh[(size_t)b * DD_ + a];
    __syncthreads();
    float acc = 0.f;
#pragma unroll 8
    for (int k = 0; k < DD_; ++k)
        acc += s_dh[k] * W_dec[(size_t)k * DA_ + a];
    att2p[(size_t)b * DA_ + a] = acc + b_dec[a] + b_enc[a];
}

// ---------------------------------------------------------------------------
// Kernel 2: GEMM 50176x512x2048 bf16 MFMA + fused relu/dot epilogue.
// 256 thr = 4 waves; tile 64x512; wave w owns cols [w*128, w*128+128).
// B frags: L2 -> VGPR directly (no LDS). A: HBM -> regs (2-iter prefetch)
// -> cvt bf16 -> LDS (dbuf, 4 KB/step). One raw barrier per K-step,
// no vmcnt drains (compiler-managed FIFO waits). 2 blocks/CU.
// ---------------------------------------------------------------------------
__global__ __launch_bounds__(256, 2) void gemm_att(
        const float* __restrict__ enc, const __hip_bfloat16* __restrict__ Bp,
        const float* __restrict__ att2p, const float* __restrict__ Wfull,
        const float* __restrict__ bfull, float* __restrict__ att) {
    __shared__ __hip_bfloat16 a_lds0[BM * KT];   // 4 KB
    __shared__ __hip_bfloat16 a_lds1[BM * KT];   // 4 KB
    __shared__ float red[BM][4];                 // 1 KB

    const int tid  = threadIdx.x;
    const int wave = tid >> 6;
    const int lane = tid & 63;
    const int g    = lane >> 4;        // k-group 0..3
    const int c    = lane & 15;
    const int block_row = blockIdx.x * BM;
    const int nbase = wave * 128;
    const int slot8 = (g ^ ((c >> 1) & 3)) * 8;

    // A staging: thread -> row ar (0..63), k-slot aq (0..3); 8 floats -> 8 bf16
    const int ar = tid >> 2;
    const int aq = tid & 3;
    const int a_woff = ar * KT + (aq ^ ((ar >> 1) & 3)) * 8;
    const float* ap = enc + (size_t)(block_row + ar) * DE_ + aq * 8;

    // B frag base for this wave/lane (units of 16 B)
    const s16x8* bp = reinterpret_cast<const s16x8*>(Bp) + (size_t)(wave * 8) * 64 + lane;

    f32x4 acc[4][8] = {};
    f32x4 pX0, pX1, pY0, pY1;     // A prefetch sets
    s16x8 bf[8];                  // current B frags

#define ISSUE_A(v0, v1, T) do {                                         \
        const int tt_ = (T) > 63 ? 63 : (T);                            \
        v0 = *reinterpret_cast<const f32x4*>(ap + tt_ * KT);            \
        v1 = *reinterpret_cast<const f32x4*>(ap + tt_ * KT + 4);        \
    } while (0)

#define ISSUE_BF(T) do {                                                \
        _Pragma("unroll")                                               \
        for (int nt_ = 0; nt_ < 8; ++nt_)                               \
            bf[nt_] = bp[((size_t)(T) * 32 + nt_) * 64];                \
    } while (0)

#define STORE_A(dst, v0, v1) do {                                       \
        s16x8 w_;                                                       \
        w_[0]=f2bf((v0).x); w_[1]=f2bf((v0).y); w_[2]=f2bf((v0).z); w_[3]=f2bf((v0).w); \
        w_[4]=f2bf((v1).x); w_[5]=f2bf((v1).y); w_[6]=f2bf((v1).z); w_[7]=f2bf((v1).w); \
        *reinterpret_cast<s16x8*>((dst) + a_woff) = w_;                 \
    } while (0)

#define AFRAGS_MFMA(abuf) do {                                          \
        s16x8 af[4];                                                    \
        _Pragma("unroll")                                               \
        for (int mt_ = 0; mt_ < 4; ++mt_)                               \
            af[mt_] = *reinterpret_cast<const s16x8*>((abuf) + (mt_*16 + c) * KT + slot8); \
        _Pragma("unroll")                                               \
        for (int nt_ = 0; nt_ < 8; ++nt_)                               \
            _Pragma("unroll")                                           \
            for (int mt_ = 0; mt_ < 4; ++mt_)                           \
                acc[mt_][nt_] = __builtin_amdgcn_mfma_f32_16x16x32_bf16(\
                                    af[mt_], bf[nt_], acc[mt_][nt_], 0, 0, 0); \
    } while (0)

#define BAR() do {                                                      \
        asm volatile("s_waitcnt lgkmcnt(0)" ::: "memory");              \
        __builtin_amdgcn_s_barrier();                                   \
        __builtin_amdgcn_sched_barrier(0);                              \
    } while (0)

    // ---- prologue ----
    ISSUE_A(pX0, pX1, 0);          // A(0)
    ISSUE_A(pY0, pY1, 1);          // A(1)
    ISSUE_BF(0);                   // B(0)
    STORE_A(a_lds0, pX0, pX1);     // waits A(0) only (FIFO)
    ISSUE_A(pX0, pX1, 2);          // A(2)
    BAR();

#pragma clang loop unroll(disable)
    for (int t = 0; t < 62; t += 2) {
        // even iter t: compute A(t)/B(t) from a_lds0/bf
        STORE_A(a_lds1, pY0, pY1);       // A(t+1) -> other buf
        ISSUE_A(pY0, pY1, t + 3);
        AFRAGS_MFMA(a_lds0);
        ISSUE_BF(t + 1);                 // after last MFMA consumed bf
        BAR();
        // odd iter t+1
        STORE_A(a_lds0, pX0, pX1);       // A(t+2)
        ISSUE_A(pX0, pX1, t + 4);
        AFRAGS_MFMA(a_lds1);
        ISSUE_BF(t + 2);
        BAR();
    }
    // t = 62: compute A(62)/B(62); stage A(63)
    STORE_A(a_lds1, pY0, pY1);
    AFRAGS_MFMA(a_lds0);
    ISSUE_BF(63);
    BAR();
    // t = 63: pure compute
    AFRAGS_MFMA(a_lds1);

    // ---- fused epilogue: att[R] = sum_n relu(att1+att2)*Wfull ----
    const int b0    = block_row / P_;
    const int b1    = min(b0 + 1, B_ - 1);
    const int split = (b0 + 1) * P_;
    float wf[8], a20[8], a21[8];
#pragma unroll
    for (int nt = 0; nt < 8; ++nt) {
        const int n = nbase + nt * 16 + c;
        wf[nt]  = Wfull[n];
        a20[nt] = att2p[(size_t)b0 * DA_ + n];
        a21[nt] = att2p[(size_t)b1 * DA_ + n];
    }
#pragma unroll
    for (int mt = 0; mt < 4; ++mt) {
#pragma unroll
        for (int q = 0; q < 4; ++q) {
            const int row_local = mt * 16 + g * 4 + q;
            const int R = block_row + row_local;
            const bool hi = (R >= split);
            float s = 0.f;
#pragma unroll
            for (int nt = 0; nt < 8; ++nt) {
                float a2 = hi ? a21[nt] : a20[nt];
                float v  = acc[mt][nt][q] + a2;
                v = fmaxf(v, 0.f);
                s += v * wf[nt];
            }
#pragma unroll
            for (int off = 1; off < 16; off <<= 1)
                s += __shfl_xor(s, off, 64);
            if (c == 0) red[row_local][wave] = s;
        }
    }
    __syncthreads();
    if (tid < BM) {
        float t = 0.f;
#pragma unroll
        for (int w = 0; w < 4; ++w) t += red[tid][w];
        att[block_row + tid] = t + bfull[0];
    }
#undef ISSUE_A
#undef ISSUE_BF
#undef STORE_A
#undef AFRAGS_MFMA
#undef BAR
}

// ---------------------------------------------------------------------------
// Kernel 3: softmax over P per batch -> alpha
// ---------------------------------------------------------------------------
__global__ __launch_bounds__(256) void softmax_kernel(
        const float* __restrict__ att, float* __restrict__ alpha) {
    const int b = blockIdx.x;
    const int t = threadIdx.x;
    __shared__ float sred[4];
    float v = (t < P_) ? att[(size_t)b * P_ + t] : -1e30f;
    float m = v;
#pragma unroll
    for (int off = 1; off < 64; off <<= 1) m = fmaxf(m, __shfl_xor(m, off, 64));
    if ((t & 63) == 0) sred[t >> 6] = m;
    __syncthreads();
    const float mall = fmaxf(fmaxf(sred[0], sred[1]), fmaxf(sred[2], sred[3]));
    __syncthreads();
    float e = (t < P_) ? expf(v - mall) : 0.f;
    float s = e;
#pragma unroll
    for (int off = 1; off < 64; off <<= 1) s += __shfl_xor(s, off, 64);
    if ((t & 63) == 0) sred[t >> 6] = s;
    __syncthreads();
    const float stot = sred[0] + sred[1] + sred[2] + sred[3];
    if (t < P_) alpha[(size_t)b * P_ + t] = e / stot;
}

// ---------------------------------------------------------------------------
// Kernel 4: context[b][e] = sum_p alpha[b][p] * enc[b][p][e]
// ---------------------------------------------------------------------------
__global__ __launch_bounds__(256) void context_kernel(
        const float* __restrict__ enc, const float* __restrict__ alpha,
        float* __restrict__ ctx) {
    const int b = blockIdx.x;
    const int e = blockIdx.y * 1024 + threadIdx.x * 4;
    __shared__ float s_alpha[P_];
    if (threadIdx.x < P_) s_alpha[threadIdx.x] = alpha[(size_t)b * P_ + threadIdx.x];
    __syncthreads();
    f32x4 acc = {0.f, 0.f, 0.f, 0.f};
    const float* base = enc + (size_t)b * P_ * DE_ + e;
#pragma unroll 4
    for (int p = 0; p < P_; ++p) {
        f32x4 v = *reinterpret_cast<const f32x4*>(base + (size_t)p * DE_);
        acc += s_alpha[p] * v;
    }
    *reinterpret_cast<f32x4*>(ctx + (size_t)b * DE_ + e) = acc;
}

// ---------------------------------------------------------------------------
extern "C" void kernel_launch(void* const* d_in, const int* in_sizes, int n_in,
                              void* d_out, int out_size, void* d_ws, size_t ws_size,
                              hipStream_t stream) {
    const float* enc    = (const float*)d_in[0];
    const float* dh     = (const float*)d_in[1];
    const float* W_enc  = (const float*)d_in[2];
    const float* b_enc  = (const float*)d_in[3];
    const float* W_dec  = (const float*)d_in[4];
    const float* b_dec  = (const float*)d_in[5];
    const float* W_full = (const float*)d_in[6];
    const float* b_full = (const float*)d_in[7];

    float* out       = (float*)d_out;
    float* ctx_out   = out;                       // [B,DE]
    float* alpha_out = out + (size_t)B_ * DE_;    // [B,P]

    char* ws = (char*)d_ws;
    __hip_bfloat16* Bp = (__hip_bfloat16*)ws;                        // 2 MB
    float* att2p = (float*)(ws + 2u * 1024 * 1024);                  // 512 KB
    float* att   = (float*)(ws + 2u * 1024 * 1024 + 512u * 1024);    // 200 KB

    pack_wenc   <<<NKT,             256, 0, stream>>>(W_enc, Bp);
    att2_kernel <<<B_,              512, 0, stream>>>(dh, W_dec, b_dec, b_enc, att2p);
    gemm_att    <<<M_ / BM,         256, 0, stream>>>(enc, Bp, att2p, W_full, b_full, att);
    softmax_kernel<<<B_,            256, 0, stream>>>(att, alpha_out);
    context_kernel<<<dim3(B_, 2),   256, 0, stream>>>(enc, alpha_out, ctx_out);
}